// Round 6
// baseline (239.009 us; speedup 1.0000x reference)
//
#include <hip/hip_runtime.h>
#include <math.h>

#define N 8192
#define D 128
#define MARGIN 0.2f
#define PD_EPS 1e-6f

#define NLAB 16
#define NSUB 32
#define CAPL 1024                    // static label-bucket capacity (counts ~512±70)
#define CAPS 512                     // static subject-bucket capacity (counts ~256±50)
#define TPL (CAPL / 64)              // 16 tiles per label bucket
#define TPS (CAPS / 64)              // 8 tiles per subject bucket
#define POSW (NLAB * TPL)            // 256 pos-mining waves
#define NEGW (NSUB * TPS)            // 256 neg-mining waves
#define MINEW (POSW + NEGW)          // 512 waves
#define MINEBLOCKS (MINEW / 4)       // 128 blocks x 4 waves

#define FBLK 64                      // k_finred blocks (64-long ticket chain)
#define RPF  (N / FBLK)              // 128 rows per finred block

typedef __attribute__((ext_vector_type(8))) short bf16x8;  // 8 bf16 = 4 VGPRs
typedef __attribute__((ext_vector_type(4))) float f32x4;

__device__ __forceinline__ unsigned short f2bf(float f) {
    unsigned u = __float_as_uint(f);
    u += 0x7FFFu + ((u >> 16) & 1u);   // round-to-nearest-even
    return (unsigned short)(u >> 16);
}
__device__ __forceinline__ unsigned umn(unsigned a, unsigned b) { return a < b ? a : b; }

// ---------------- kernel 1: normalize + static-layout scatter (fused) --------
// 2048 blocks x 4 rows. Slot = bucket_base + rank; rank from one global
// atomicAdd per (row,bucket). Counters are pre-memset to 0xFF (= -1), so
// rank = atomicAdd(c,1)+1 starts at 0 with no zeroing kernel. Pad slots keep
// meta=perm=-1 from the same memset. No scans, no wave tables, no spin:
// round-1/5 showed in-kernel global sync costs 50-150us — layout is static now.
__global__ __launch_bounds__(256) void k_scatnorm(const float* __restrict__ z,
                                                  const int* __restrict__ labels,
                                                  const int* __restrict__ subjects,
                                                  unsigned short* __restrict__ znbL,
                                                  unsigned short* __restrict__ znbS,
                                                  float* __restrict__ invn,
                                                  int* __restrict__ metaL, int* __restrict__ permL,
                                                  int* __restrict__ metaS, int* __restrict__ permS,
                                                  int* __restrict__ cnt,
                                                  unsigned* __restrict__ tick) {
    if (blockIdx.x == 0 && threadIdx.x == 0) tick[3] = 0u;   // arm finred ticket (stream-ordered)
    int row  = blockIdx.x * 4 + (threadIdx.x >> 6);
    int lane = threadIdx.x & 63;
    float2 v = ((const float2*)(z + (size_t)row * D))[lane];
    float ss = v.x * v.x + v.y * v.y;
    #pragma unroll
    for (int m = 1; m < 64; m <<= 1) ss += __shfl_xor(ss, m, 64);
    float norm = fmaxf(sqrtf(ss), 1e-12f);
    ushort2 b; b.x = f2bf(v.x / norm); b.y = f2bf(v.y / norm);

    int slotL = 0, slotS = 0;
    if (lane == 0) {
        int lab = labels[row], sub = subjects[row];
        int me = lab * 32 + sub;
        slotL = lab * CAPL + atomicAdd(&cnt[lab], 1) + 1;        // rank 0.. (cnt starts -1)
        slotS = sub * CAPS + atomicAdd(&cnt[NLAB + sub], 1) + 1;
        metaL[slotL] = me; permL[slotL] = row;
        metaS[slotS] = me; permS[slotS] = row;
        invn[row] = 1.0f / norm;
    }
    slotL = __shfl(slotL, 0, 64);
    slotS = __shfl(slotS, 0, 64);
    ((ushort2*)(znbL + (size_t)slotL * D))[lane] = b;
    ((ushort2*)(znbS + (size_t)slotS * D))[lane] = b;
}

// ---------------- kernel 2: bucketed MFMA mining (r4 body, static mapping) ---
// Wave w < POSW: pos-mining in label bucket b=w>>4, anchor tile q=w&15.
// Wave w >= POSW: neg-mining in subject bucket b=(w-POSW)>>3, tile q&7.
// Ranks are a dense prefix per bucket, so: anchor tile all-pad <=> mt[ab]<0
// (early exit); j sweep breaks at first all-pad tile. Pad meta=-1 makes
// x=(mi^mj) >= 0xFFFFFE00 (fails (x-1u)<thr for any real partner; pad^pad
// gives x=0, also fails). Write guard (unsigned)orig<N kills pad anchors.
// Keys carry ORIGINAL j -> selections bit-identical to the passing r4 kernel.
__global__ __launch_bounds__(256) void k_mine(const unsigned short* __restrict__ znbL,
                                              const unsigned short* __restrict__ znbS,
                                              const int* __restrict__ metaL, const int* __restrict__ permL,
                                              const int* __restrict__ metaS, const int* __restrict__ permS,
                                              unsigned* __restrict__ posk, unsigned* __restrict__ negk) {
    const int wave = threadIdx.x >> 6;
    const int lane = threadIdx.x & 63;
    const int w    = blockIdx.x * 4 + wave;
    const bool isPos = (w < POSW);
    int ab, jb, maxT;
    if (isPos) { int b = w >> 4, q = w & 15;        ab = b * CAPL + q * 64; jb = b * CAPL; maxT = TPL; }
    else       { int w2 = w - POSW, b = w2 >> 3, q = w2 & 7; ab = b * CAPS + q * 64; jb = b * CAPS; maxT = TPS; }
    const unsigned short* zb = isPos ? znbL : znbS;
    const int* mt = isPos ? metaL : metaS;
    const int* pm = isPos ? permL : permS;
    const unsigned thr = isPos ? 31u : 1023u;
    const unsigned inv = isPos ? 0u : 0xFFFFFFFFu;

    if (mt[ab] < 0) return;                       // anchor tile entirely pads (uniform)

    const int m    = lane & 15;
    const int quad = lane >> 4;

    bf16x8 afrag[4][4];
    #pragma unroll
    for (int u = 0; u < 4; ++u)
        #pragma unroll
        for (int s = 0; s < 4; ++s)
            afrag[u][s] = *(const bf16x8*)(zb + (size_t)(ab + u * 16 + m) * D + s * 32 + quad * 8);

    int mi[16];
    #pragma unroll
    for (int u = 0; u < 4; ++u)
        #pragma unroll
        for (int r = 0; r < 4; ++r)
            mi[u * 4 + r] = mt[ab + u * 16 + quad * 4 + r];

    unsigned best[16];
    #pragma unroll
    for (int s = 0; s < 16; ++s) best[s] = 0xFFFFFFFFu;

    for (int t = 0; t < maxT; ++t) {
        const int jt = jb + t * 64;
        if (mt[jt] < 0) break;                    // rest of bucket is pads (uniform)
        int mjv[4], jov[4];
        #pragma unroll
        for (int v = 0; v < 4; ++v) {
            int jr = jt + v * 16 + m;
            mjv[v] = mt[jr];
            jov[v] = pm[jr];
        }

        f32x4 acc[4][4];
        #pragma unroll
        for (int u = 0; u < 4; ++u)
            #pragma unroll
            for (int v = 0; v < 4; ++v)
                acc[u][v] = (f32x4){0.f, 0.f, 0.f, 0.f};

        #pragma unroll
        for (int s = 0; s < 4; ++s) {
            bf16x8 bf[4];
            #pragma unroll
            for (int v = 0; v < 4; ++v)
                bf[v] = *(const bf16x8*)(zb + (size_t)(jt + v * 16 + m) * D + s * 32 + quad * 8);
            #pragma unroll
            for (int u = 0; u < 4; ++u)
                #pragma unroll
                for (int v = 0; v < 4; ++v)
                    acc[u][v] = __builtin_amdgcn_mfma_f32_16x16x32_bf16(afrag[u][s], bf[v], acc[u][v], 0, 0, 0);
        }

        // epilogue: C/D layout col=lane&15 (j), row=quad*4+r (anchor) — m89-verified
        #pragma unroll
        for (int v = 0; v < 4; ++v) {
            #pragma unroll
            for (int u = 0; u < 4; ++u)
                #pragma unroll
                for (int r = 0; r < 4; ++r) {
                    float dot = acc[u][v][r];
                    unsigned key = (((__float_as_uint(dot + 2.0f)) & 0xFFFFE000u) | (unsigned)jov[v]) ^ inv;
                    unsigned x = (unsigned)(mi[u * 4 + r] ^ mjv[v]);
                    bool c = (x - 1u) < thr;      // excludes diagonal, same-meta, and pads
                    best[u * 4 + r] = umn(best[u * 4 + r], c ? key : 0xFFFFFFFFu);
                }
        }
    }

    // merge across the 16 lanes (different j) sharing each (quad, slot)
    #pragma unroll
    for (int mm = 1; mm < 16; mm <<= 1)
        #pragma unroll
        for (int s = 0; s < 16; ++s)
            best[s] = umn(best[s], (unsigned)__shfl_xor((int)best[s], mm, 64));

    if (m == 0) {
        unsigned* dst = isPos ? posk : negk;
        #pragma unroll
        for (int u = 0; u < 4; ++u)
            #pragma unroll
            for (int r = 0; r < 4; ++r) {
                int orig = pm[ab + u * 16 + quad * 4 + r];
                if ((unsigned)orig < (unsigned)N)          // pad anchors: perm=-1
                    dst[orig] = best[u * 4 + r] ^ inv;
            }
    }
}

// ---------------- kernel 3: hinge + last-block deterministic reduce ----------
// 64 blocks; ticket chain of 64 (r5's finred structure — never implicated).
// Last block runs the r4 k_reduce body verbatim -> bit-identical output.
__global__ __launch_bounds__(256) void k_finred(const float* __restrict__ z,
                                                const float* __restrict__ invn,
                                                const unsigned* __restrict__ posk,
                                                const unsigned* __restrict__ negk,
                                                float* __restrict__ per, float* __restrict__ vld,
                                                unsigned* __restrict__ tick,
                                                float* __restrict__ out) {
    __shared__ float s1[256], s2[256];
    __shared__ int amLast;
    const int t  = threadIdx.x;
    const int wv = t >> 6, lane = t & 63;
    const int base = blockIdx.x * RPF + wv * (RPF / 4);

    #pragma unroll 2
    for (int rr = 0; rr < RPF / 4; ++rr) {
        int row = base + rr;
        unsigned mp = posk[row];
        unsigned mn = negk[row];
        bool valid = (mp != 0xFFFFFFFFu) && (mn != 0u);
        int pi = valid ? (int)(mp & 8191u) : 0;
        int ni = valid ? (int)(mn & 8191u) : 0;
        float ia = invn[row], ip = invn[pi], iq = invn[ni];
        float2 a = ((const float2*)(z + (size_t)row * D))[lane];
        float2 p = ((const float2*)(z + (size_t)pi  * D))[lane];
        float2 q = ((const float2*)(z + (size_t)ni  * D))[lane];
        float dx = a.x * ia - p.x * ip + PD_EPS, dy = a.y * ia - p.y * ip + PD_EPS;
        float sap = dx * dx + dy * dy;
        dx = a.x * ia - q.x * iq + PD_EPS; dy = a.y * ia - q.y * iq + PD_EPS;
        float san = dx * dx + dy * dy;
        #pragma unroll
        for (int m = 1; m < 64; m <<= 1) {
            sap += __shfl_xor(sap, m, 64);
            san += __shfl_xor(san, m, 64);
        }
        if (lane == 0) {
            float l = fmaxf(sqrtf(sap) - sqrtf(san) + MARGIN, 0.0f);
            per[row] = valid ? l : 0.0f;
            vld[row] = valid ? 1.0f : 0.0f;
        }
    }

    __threadfence();
    __syncthreads();
    if (t == 0) amLast = (atomicInc(tick + 3, FBLK - 1) == FBLK - 1);  // wraps to 0
    __syncthreads();
    if (amLast) {
        __threadfence();   // acquire all blocks' per/vld
        float a = 0.f, b = 0.f;
        for (int i = t; i < N; i += 256) { a += per[i]; b += vld[i]; }
        s1[t] = a; s2[t] = b;
        __syncthreads();
        for (int w = 128; w > 0; w >>= 1) {
            if (t < w) { s1[t] += s1[t + w]; s2[t] += s2[t + w]; }
            __syncthreads();
        }
        if (t == 0) {
            float cnt = s2[0];
            out[0] = (cnt > 0.f) ? s1[0] / fmaxf(cnt, 1.f) : 0.f;
        }
    }
}

extern "C" void kernel_launch(void* const* d_in, const int* in_sizes, int n_in,
                              void* d_out, int out_size, void* d_ws, size_t ws_size,
                              hipStream_t stream) {
    const float* z        = (const float*)d_in[0];
    const int*   labels   = (const int*)d_in[1];
    const int*   subjects = (const int*)d_in[2];
    float* out = (float*)d_out;

    char* ws = (char*)d_ws;
    size_t o = 0;
    unsigned short* znbL = (unsigned short*)(ws + o); o += (size_t)NLAB * CAPL * D * 2;  // 4 MB
    unsigned short* znbS = (unsigned short*)(ws + o); o += (size_t)NSUB * CAPS * D * 2;  // 4 MB
    float* invn = (float*)(ws + o); o += N * 4;
    unsigned* posk = (unsigned*)(ws + o); o += N * 4;
    unsigned* negk = (unsigned*)(ws + o); o += N * 4;
    float* per = (float*)(ws + o); o += N * 4;
    float* vld = (float*)(ws + o); o += N * 4;
    // ---- 0xFF-memset region: meta/perm pads (-1) + counters (-1) ----
    char* padbase = ws + o;
    int* metaL = (int*)(ws + o); o += NLAB * CAPL * 4;    // 64 KB
    int* permL = (int*)(ws + o); o += NLAB * CAPL * 4;    // 64 KB
    int* metaS = (int*)(ws + o); o += NSUB * CAPS * 4;    // 64 KB
    int* permS = (int*)(ws + o); o += NSUB * CAPS * 4;    // 64 KB
    int* cnt   = (int*)(ws + o); o += 256;
    size_t padbytes = (size_t)((char*)(ws + o) - padbase);
    unsigned* tick = (unsigned*)(ws + o); o += 64;        // total ~8.7 MB

    hipMemsetAsync(padbase, 0xFF, padbytes, stream);
    k_scatnorm<<<dim3(N / 4), dim3(256), 0, stream>>>(z, labels, subjects, znbL, znbS, invn,
                                                      metaL, permL, metaS, permS, cnt, tick);
    k_mine<<<dim3(MINEBLOCKS), dim3(256), 0, stream>>>(znbL, znbS, metaL, permL, metaS, permS,
                                                       posk, negk);
    k_finred<<<dim3(FBLK), dim3(256), 0, stream>>>(z, invn, posk, negk, per, vld, tick, out);
}

// Round 7
// 144.730 us; speedup vs baseline: 1.6514x; 1.6514x over previous
//
#include <hip/hip_runtime.h>
#include <math.h>

#define N 8192
#define D 128
#define MARGIN 0.2f
#define PD_EPS 1e-6f

#define NLAB 16
#define NSUB 32
#define CAPL 1024                    // static label-bucket capacity (counts ~512±70)
#define CAPS 512                     // static subject-bucket capacity (counts ~256±50)
#define TPL (CAPL / 64)              // 16 tiles per label bucket
#define TPS (CAPS / 64)              // 8 tiles per subject bucket
#define POSW (NLAB * TPL)            // 256 pos-mining waves
#define NEGW (NSUB * TPS)            // 256 neg-mining waves
#define MINEW (POSW + NEGW)          // 512 waves
#define MINEBLOCKS (MINEW / 4)       // 128 blocks x 4 waves

#define CSTRIDE 32                   // one counter per 128B cacheline (r6: packed
                                     // counters -> all atomics on 2 lines -> one
                                     // RMW per ~15cy globally = 104us. Guideline 12.)

#define FBLK 64                      // k_finred blocks (64-long ticket chain)
#define RPF  (N / FBLK)              // 128 rows per finred block

typedef __attribute__((ext_vector_type(8))) short bf16x8;  // 8 bf16 = 4 VGPRs
typedef __attribute__((ext_vector_type(4))) float f32x4;

__device__ __forceinline__ unsigned short f2bf(float f) {
    unsigned u = __float_as_uint(f);
    u += 0x7FFFu + ((u >> 16) & 1u);   // round-to-nearest-even
    return (unsigned short)(u >> 16);
}
__device__ __forceinline__ unsigned umn(unsigned a, unsigned b) { return a < b ? a : b; }

// ---------------- kernel 1: normalize + static-layout scatter (fused) --------
// 2048 blocks x 4 rows. Slot = bucket_base + rank; rank from one global
// atomicAdd per (row,bucket), counters PADDED one per 128B cacheline so the
// ~512 same-address RMWs per bucket serialize independently per line (~2us)
// instead of all 16K serializing on 2 lines (~104us, round-6 post-mortem).
// Counters pre-memset to 0xFF (= -1): rank = atomicAdd(c,1)+1 starts at 0.
__global__ __launch_bounds__(256) void k_scatnorm(const float* __restrict__ z,
                                                  const int* __restrict__ labels,
                                                  const int* __restrict__ subjects,
                                                  unsigned short* __restrict__ znbL,
                                                  unsigned short* __restrict__ znbS,
                                                  float* __restrict__ invn,
                                                  int* __restrict__ metaL, int* __restrict__ permL,
                                                  int* __restrict__ metaS, int* __restrict__ permS,
                                                  int* __restrict__ cnt,
                                                  unsigned* __restrict__ tick) {
    if (blockIdx.x == 0 && threadIdx.x == 0) tick[3] = 0u;   // arm finred ticket (stream-ordered)
    int row  = blockIdx.x * 4 + (threadIdx.x >> 6);
    int lane = threadIdx.x & 63;
    float2 v = ((const float2*)(z + (size_t)row * D))[lane];
    float ss = v.x * v.x + v.y * v.y;
    #pragma unroll
    for (int m = 1; m < 64; m <<= 1) ss += __shfl_xor(ss, m, 64);
    float norm = fmaxf(sqrtf(ss), 1e-12f);
    ushort2 b; b.x = f2bf(v.x / norm); b.y = f2bf(v.y / norm);

    int slotL = 0, slotS = 0;
    if (lane == 0) {
        int lab = labels[row], sub = subjects[row];
        int me = lab * 32 + sub;
        slotL = lab * CAPL + atomicAdd(&cnt[lab * CSTRIDE], 1) + 1;          // rank 0..
        slotS = sub * CAPS + atomicAdd(&cnt[(NLAB + sub) * CSTRIDE], 1) + 1;
        metaL[slotL] = me; permL[slotL] = row;
        metaS[slotS] = me; permS[slotS] = row;
        invn[row] = 1.0f / norm;
    }
    slotL = __shfl(slotL, 0, 64);
    slotS = __shfl(slotS, 0, 64);
    ((ushort2*)(znbL + (size_t)slotL * D))[lane] = b;
    ((ushort2*)(znbS + (size_t)slotS * D))[lane] = b;
}

// ---------------- kernel 2: bucketed MFMA mining (r4 body, static mapping) ---
// Wave w < POSW: pos-mining in label bucket b=w>>4, anchor tile q=w&15.
// Wave w >= POSW: neg-mining in subject bucket b=(w-POSW)>>3, tile q&7.
// Ranks are a dense prefix per bucket, so: anchor tile all-pad <=> mt[ab]<0
// (early exit); j sweep breaks at first all-pad tile. Pad meta=-1 makes
// x=(mi^mj) >= 0xFFFFFE00 (fails (x-1u)<thr for any real partner; pad^pad
// gives x=0, also fails). Write guard (unsigned)orig<N kills pad anchors.
// Keys carry ORIGINAL j -> selections bit-identical to the passing r4 kernel.
__global__ __launch_bounds__(256) void k_mine(const unsigned short* __restrict__ znbL,
                                              const unsigned short* __restrict__ znbS,
                                              const int* __restrict__ metaL, const int* __restrict__ permL,
                                              const int* __restrict__ metaS, const int* __restrict__ permS,
                                              unsigned* __restrict__ posk, unsigned* __restrict__ negk) {
    const int wave = threadIdx.x >> 6;
    const int lane = threadIdx.x & 63;
    const int w    = blockIdx.x * 4 + wave;
    const bool isPos = (w < POSW);
    int ab, jb, maxT;
    if (isPos) { int b = w >> 4, q = w & 15;        ab = b * CAPL + q * 64; jb = b * CAPL; maxT = TPL; }
    else       { int w2 = w - POSW, b = w2 >> 3, q = w2 & 7; ab = b * CAPS + q * 64; jb = b * CAPS; maxT = TPS; }
    const unsigned short* zb = isPos ? znbL : znbS;
    const int* mt = isPos ? metaL : metaS;
    const int* pm = isPos ? permL : permS;
    const unsigned thr = isPos ? 31u : 1023u;
    const unsigned inv = isPos ? 0u : 0xFFFFFFFFu;

    if (mt[ab] < 0) return;                       // anchor tile entirely pads (uniform)

    const int m    = lane & 15;
    const int quad = lane >> 4;

    bf16x8 afrag[4][4];
    #pragma unroll
    for (int u = 0; u < 4; ++u)
        #pragma unroll
        for (int s = 0; s < 4; ++s)
            afrag[u][s] = *(const bf16x8*)(zb + (size_t)(ab + u * 16 + m) * D + s * 32 + quad * 8);

    int mi[16];
    #pragma unroll
    for (int u = 0; u < 4; ++u)
        #pragma unroll
        for (int r = 0; r < 4; ++r)
            mi[u * 4 + r] = mt[ab + u * 16 + quad * 4 + r];

    unsigned best[16];
    #pragma unroll
    for (int s = 0; s < 16; ++s) best[s] = 0xFFFFFFFFu;

    for (int t = 0; t < maxT; ++t) {
        const int jt = jb + t * 64;
        if (mt[jt] < 0) break;                    // rest of bucket is pads (uniform)
        int mjv[4], jov[4];
        #pragma unroll
        for (int v = 0; v < 4; ++v) {
            int jr = jt + v * 16 + m;
            mjv[v] = mt[jr];
            jov[v] = pm[jr];
        }

        f32x4 acc[4][4];
        #pragma unroll
        for (int u = 0; u < 4; ++u)
            #pragma unroll
            for (int v = 0; v < 4; ++v)
                acc[u][v] = (f32x4){0.f, 0.f, 0.f, 0.f};

        #pragma unroll
        for (int s = 0; s < 4; ++s) {
            bf16x8 bf[4];
            #pragma unroll
            for (int v = 0; v < 4; ++v)
                bf[v] = *(const bf16x8*)(zb + (size_t)(jt + v * 16 + m) * D + s * 32 + quad * 8);
            #pragma unroll
            for (int u = 0; u < 4; ++u)
                #pragma unroll
                for (int v = 0; v < 4; ++v)
                    acc[u][v] = __builtin_amdgcn_mfma_f32_16x16x32_bf16(afrag[u][s], bf[v], acc[u][v], 0, 0, 0);
        }

        // epilogue: C/D layout col=lane&15 (j), row=quad*4+r (anchor) — m89-verified
        #pragma unroll
        for (int v = 0; v < 4; ++v) {
            #pragma unroll
            for (int u = 0; u < 4; ++u)
                #pragma unroll
                for (int r = 0; r < 4; ++r) {
                    float dot = acc[u][v][r];
                    unsigned key = (((__float_as_uint(dot + 2.0f)) & 0xFFFFE000u) | (unsigned)jov[v]) ^ inv;
                    unsigned x = (unsigned)(mi[u * 4 + r] ^ mjv[v]);
                    bool c = (x - 1u) < thr;      // excludes diagonal, same-meta, and pads
                    best[u * 4 + r] = umn(best[u * 4 + r], c ? key : 0xFFFFFFFFu);
                }
        }
    }

    // merge across the 16 lanes (different j) sharing each (quad, slot)
    #pragma unroll
    for (int mm = 1; mm < 16; mm <<= 1)
        #pragma unroll
        for (int s = 0; s < 16; ++s)
            best[s] = umn(best[s], (unsigned)__shfl_xor((int)best[s], mm, 64));

    if (m == 0) {
        unsigned* dst = isPos ? posk : negk;
        #pragma unroll
        for (int u = 0; u < 4; ++u)
            #pragma unroll
            for (int r = 0; r < 4; ++r) {
                int orig = pm[ab + u * 16 + quad * 4 + r];
                if ((unsigned)orig < (unsigned)N)          // pad anchors: perm=-1
                    dst[orig] = best[u * 4 + r] ^ inv;
            }
    }
}

// ---------------- kernel 3: hinge + last-block deterministic reduce ----------
// 64 blocks; ticket chain of 64 (r5's finred structure — never implicated).
// Last block runs the r4 k_reduce body verbatim -> bit-identical output.
__global__ __launch_bounds__(256) void k_finred(const float* __restrict__ z,
                                                const float* __restrict__ invn,
                                                const unsigned* __restrict__ posk,
                                                const unsigned* __restrict__ negk,
                                                float* __restrict__ per, float* __restrict__ vld,
                                                unsigned* __restrict__ tick,
                                                float* __restrict__ out) {
    __shared__ float s1[256], s2[256];
    __shared__ int amLast;
    const int t  = threadIdx.x;
    const int wv = t >> 6, lane = t & 63;
    const int base = blockIdx.x * RPF + wv * (RPF / 4);

    #pragma unroll 2
    for (int rr = 0; rr < RPF / 4; ++rr) {
        int row = base + rr;
        unsigned mp = posk[row];
        unsigned mn = negk[row];
        bool valid = (mp != 0xFFFFFFFFu) && (mn != 0u);
        int pi = valid ? (int)(mp & 8191u) : 0;
        int ni = valid ? (int)(mn & 8191u) : 0;
        float ia = invn[row], ip = invn[pi], iq = invn[ni];
        float2 a = ((const float2*)(z + (size_t)row * D))[lane];
        float2 p = ((const float2*)(z + (size_t)pi  * D))[lane];
        float2 q = ((const float2*)(z + (size_t)ni  * D))[lane];
        float dx = a.x * ia - p.x * ip + PD_EPS, dy = a.y * ia - p.y * ip + PD_EPS;
        float sap = dx * dx + dy * dy;
        dx = a.x * ia - q.x * iq + PD_EPS; dy = a.y * ia - q.y * iq + PD_EPS;
        float san = dx * dx + dy * dy;
        #pragma unroll
        for (int m = 1; m < 64; m <<= 1) {
            sap += __shfl_xor(sap, m, 64);
            san += __shfl_xor(san, m, 64);
        }
        if (lane == 0) {
            float l = fmaxf(sqrtf(sap) - sqrtf(san) + MARGIN, 0.0f);
            per[row] = valid ? l : 0.0f;
            vld[row] = valid ? 1.0f : 0.0f;
        }
    }

    __threadfence();
    __syncthreads();
    if (t == 0) amLast = (atomicInc(tick + 3, FBLK - 1) == FBLK - 1);  // wraps to 0
    __syncthreads();
    if (amLast) {
        __threadfence();   // acquire all blocks' per/vld
        float a = 0.f, b = 0.f;
        for (int i = t; i < N; i += 256) { a += per[i]; b += vld[i]; }
        s1[t] = a; s2[t] = b;
        __syncthreads();
        for (int w = 128; w > 0; w >>= 1) {
            if (t < w) { s1[t] += s1[t + w]; s2[t] += s2[t + w]; }
            __syncthreads();
        }
        if (t == 0) {
            float cnt = s2[0];
            out[0] = (cnt > 0.f) ? s1[0] / fmaxf(cnt, 1.f) : 0.f;
        }
    }
}

extern "C" void kernel_launch(void* const* d_in, const int* in_sizes, int n_in,
                              void* d_out, int out_size, void* d_ws, size_t ws_size,
                              hipStream_t stream) {
    const float* z        = (const float*)d_in[0];
    const int*   labels   = (const int*)d_in[1];
    const int*   subjects = (const int*)d_in[2];
    float* out = (float*)d_out;

    char* ws = (char*)d_ws;
    size_t o = 0;
    unsigned short* znbL = (unsigned short*)(ws + o); o += (size_t)NLAB * CAPL * D * 2;  // 4 MB
    unsigned short* znbS = (unsigned short*)(ws + o); o += (size_t)NSUB * CAPS * D * 2;  // 4 MB
    float* invn = (float*)(ws + o); o += N * 4;
    unsigned* posk = (unsigned*)(ws + o); o += N * 4;
    unsigned* negk = (unsigned*)(ws + o); o += N * 4;
    float* per = (float*)(ws + o); o += N * 4;
    float* vld = (float*)(ws + o); o += N * 4;
    // ---- 0xFF-memset region: meta/perm pads (-1) + padded counters (-1) ----
    char* padbase = ws + o;
    int* metaL = (int*)(ws + o); o += NLAB * CAPL * 4;    // 64 KB
    int* permL = (int*)(ws + o); o += NLAB * CAPL * 4;    // 64 KB
    int* metaS = (int*)(ws + o); o += NSUB * CAPS * 4;    // 64 KB
    int* permS = (int*)(ws + o); o += NSUB * CAPS * 4;    // 64 KB
    int* cnt   = (int*)(ws + o); o += (NLAB + NSUB) * CSTRIDE * 4;   // 6 KB, 1 cnt / 128B line
    size_t padbytes = (size_t)((char*)(ws + o) - padbase);
    unsigned* tick = (unsigned*)(ws + o); o += 64;        // total ~8.7 MB

    hipMemsetAsync(padbase, 0xFF, padbytes, stream);
    k_scatnorm<<<dim3(N / 4), dim3(256), 0, stream>>>(z, labels, subjects, znbL, znbS, invn,
                                                      metaL, permL, metaS, permS, cnt, tick);
    k_mine<<<dim3(MINEBLOCKS), dim3(256), 0, stream>>>(znbL, znbS, metaL, permL, metaS, permS,
                                                       posk, negk);
    k_finred<<<dim3(FBLK), dim3(256), 0, stream>>>(z, invn, posk, negk, per, vld, tick, out);
}

// Round 8
// 127.561 us; speedup vs baseline: 1.8737x; 1.1346x over previous
//
#include <hip/hip_runtime.h>
#include <math.h>

#define N 8192
#define D 128
#define MARGIN 0.2f
#define PD_EPS 1e-6f

#define NLAB 16
#define NSUB 32
#define CAPL 1024                    // static label-bucket capacity (counts ~512±70)
#define CAPS 512                     // static subject-bucket capacity (counts ~256±50)
#define TPL (CAPL / 64)              // 16 tiles per label bucket
#define TPS (CAPS / 64)              // 8 tiles per subject bucket
#define POSW (NLAB * TPL)            // 256 pos-mining waves
#define NEGW (NSUB * TPS)            // 256 neg-mining waves
#define MINEW (POSW + NEGW)          // 512 waves
#define MINEBLOCKS (MINEW / 4)       // 128 blocks x 4 waves

#define CSTRIDE 32                   // one counter per 128B cacheline (r6: packed
                                     // counters -> all atomics on 2 lines -> one
                                     // RMW per ~15cy globally = 104us. Guideline 12.)

#define FBLK 512                     // r7: FBLK=64 -> 256 waves, 32 serial dependent
                                     // gather iters each = 43us latency-bound.
                                     // 512 blocks = 2 blocks/CU, 4 rows/wave unrolled.
#define RPF  (N / FBLK)              // 16 rows per finred block (4 per wave)

typedef __attribute__((ext_vector_type(8))) short bf16x8;  // 8 bf16 = 4 VGPRs
typedef __attribute__((ext_vector_type(4))) float f32x4;

__device__ __forceinline__ unsigned short f2bf(float f) {
    unsigned u = __float_as_uint(f);
    u += 0x7FFFu + ((u >> 16) & 1u);   // round-to-nearest-even
    return (unsigned short)(u >> 16);
}
__device__ __forceinline__ unsigned umn(unsigned a, unsigned b) { return a < b ? a : b; }

// ---------------- kernel 1: normalize + static-layout scatter (fused) --------
// 2048 blocks x 4 rows. Slot = bucket_base + rank; rank from one global
// atomicAdd per (row,bucket), counters padded one per 128B cacheline (r7 fix,
// verified: scatnorm dropped out of top-5). Counters pre-memset to 0xFF (=-1):
// rank = atomicAdd(c,1)+1 starts at 0.
__global__ __launch_bounds__(256) void k_scatnorm(const float* __restrict__ z,
                                                  const int* __restrict__ labels,
                                                  const int* __restrict__ subjects,
                                                  unsigned short* __restrict__ znbL,
                                                  unsigned short* __restrict__ znbS,
                                                  float* __restrict__ invn,
                                                  int* __restrict__ metaL, int* __restrict__ permL,
                                                  int* __restrict__ metaS, int* __restrict__ permS,
                                                  int* __restrict__ cnt,
                                                  unsigned* __restrict__ tick) {
    if (blockIdx.x == 0 && threadIdx.x == 0) tick[3] = 0u;   // arm finred ticket (stream-ordered)
    int row  = blockIdx.x * 4 + (threadIdx.x >> 6);
    int lane = threadIdx.x & 63;
    float2 v = ((const float2*)(z + (size_t)row * D))[lane];
    float ss = v.x * v.x + v.y * v.y;
    #pragma unroll
    for (int m = 1; m < 64; m <<= 1) ss += __shfl_xor(ss, m, 64);
    float norm = fmaxf(sqrtf(ss), 1e-12f);
    ushort2 b; b.x = f2bf(v.x / norm); b.y = f2bf(v.y / norm);

    int slotL = 0, slotS = 0;
    if (lane == 0) {
        int lab = labels[row], sub = subjects[row];
        int me = lab * 32 + sub;
        slotL = lab * CAPL + atomicAdd(&cnt[lab * CSTRIDE], 1) + 1;          // rank 0..
        slotS = sub * CAPS + atomicAdd(&cnt[(NLAB + sub) * CSTRIDE], 1) + 1;
        metaL[slotL] = me; permL[slotL] = row;
        metaS[slotS] = me; permS[slotS] = row;
        invn[row] = 1.0f / norm;
    }
    slotL = __shfl(slotL, 0, 64);
    slotS = __shfl(slotS, 0, 64);
    ((ushort2*)(znbL + (size_t)slotL * D))[lane] = b;
    ((ushort2*)(znbS + (size_t)slotS * D))[lane] = b;
}

// ---------------- kernel 2: bucketed MFMA mining (r4 body, static mapping) ---
// Wave w < POSW: pos-mining in label bucket b=w>>4, anchor tile q=w&15.
// Wave w >= POSW: neg-mining in subject bucket b=(w-POSW)>>3, tile q&7.
// Ranks are a dense prefix per bucket, so: anchor tile all-pad <=> mt[ab]<0
// (early exit); j sweep breaks at first all-pad tile. Pad meta=-1 makes
// x=(mi^mj) >= 0xFFFFFE00 (fails (x-1u)<thr for any real partner; pad^pad
// gives x=0, also fails). Write guard (unsigned)orig<N kills pad anchors.
// Keys carry ORIGINAL j -> selections bit-identical to the passing r4 kernel.
__global__ __launch_bounds__(256) void k_mine(const unsigned short* __restrict__ znbL,
                                              const unsigned short* __restrict__ znbS,
                                              const int* __restrict__ metaL, const int* __restrict__ permL,
                                              const int* __restrict__ metaS, const int* __restrict__ permS,
                                              unsigned* __restrict__ posk, unsigned* __restrict__ negk) {
    const int wave = threadIdx.x >> 6;
    const int lane = threadIdx.x & 63;
    const int w    = blockIdx.x * 4 + wave;
    const bool isPos = (w < POSW);
    int ab, jb, maxT;
    if (isPos) { int b = w >> 4, q = w & 15;        ab = b * CAPL + q * 64; jb = b * CAPL; maxT = TPL; }
    else       { int w2 = w - POSW, b = w2 >> 3, q = w2 & 7; ab = b * CAPS + q * 64; jb = b * CAPS; maxT = TPS; }
    const unsigned short* zb = isPos ? znbL : znbS;
    const int* mt = isPos ? metaL : metaS;
    const int* pm = isPos ? permL : permS;
    const unsigned thr = isPos ? 31u : 1023u;
    const unsigned inv = isPos ? 0u : 0xFFFFFFFFu;

    if (mt[ab] < 0) return;                       // anchor tile entirely pads (uniform)

    const int m    = lane & 15;
    const int quad = lane >> 4;

    bf16x8 afrag[4][4];
    #pragma unroll
    for (int u = 0; u < 4; ++u)
        #pragma unroll
        for (int s = 0; s < 4; ++s)
            afrag[u][s] = *(const bf16x8*)(zb + (size_t)(ab + u * 16 + m) * D + s * 32 + quad * 8);

    int mi[16];
    #pragma unroll
    for (int u = 0; u < 4; ++u)
        #pragma unroll
        for (int r = 0; r < 4; ++r)
            mi[u * 4 + r] = mt[ab + u * 16 + quad * 4 + r];

    unsigned best[16];
    #pragma unroll
    for (int s = 0; s < 16; ++s) best[s] = 0xFFFFFFFFu;

    for (int t = 0; t < maxT; ++t) {
        const int jt = jb + t * 64;
        if (mt[jt] < 0) break;                    // rest of bucket is pads (uniform)
        int mjv[4], jov[4];
        #pragma unroll
        for (int v = 0; v < 4; ++v) {
            int jr = jt + v * 16 + m;
            mjv[v] = mt[jr];
            jov[v] = pm[jr];
        }

        f32x4 acc[4][4];
        #pragma unroll
        for (int u = 0; u < 4; ++u)
            #pragma unroll
            for (int v = 0; v < 4; ++v)
                acc[u][v] = (f32x4){0.f, 0.f, 0.f, 0.f};

        #pragma unroll
        for (int s = 0; s < 4; ++s) {
            bf16x8 bf[4];
            #pragma unroll
            for (int v = 0; v < 4; ++v)
                bf[v] = *(const bf16x8*)(zb + (size_t)(jt + v * 16 + m) * D + s * 32 + quad * 8);
            #pragma unroll
            for (int u = 0; u < 4; ++u)
                #pragma unroll
                for (int v = 0; v < 4; ++v)
                    acc[u][v] = __builtin_amdgcn_mfma_f32_16x16x32_bf16(afrag[u][s], bf[v], acc[u][v], 0, 0, 0);
        }

        // epilogue: C/D layout col=lane&15 (j), row=quad*4+r (anchor) — m89-verified
        #pragma unroll
        for (int v = 0; v < 4; ++v) {
            #pragma unroll
            for (int u = 0; u < 4; ++u)
                #pragma unroll
                for (int r = 0; r < 4; ++r) {
                    float dot = acc[u][v][r];
                    unsigned key = (((__float_as_uint(dot + 2.0f)) & 0xFFFFE000u) | (unsigned)jov[v]) ^ inv;
                    unsigned x = (unsigned)(mi[u * 4 + r] ^ mjv[v]);
                    bool c = (x - 1u) < thr;      // excludes diagonal, same-meta, and pads
                    best[u * 4 + r] = umn(best[u * 4 + r], c ? key : 0xFFFFFFFFu);
                }
        }
    }

    // merge across the 16 lanes (different j) sharing each (quad, slot)
    #pragma unroll
    for (int mm = 1; mm < 16; mm <<= 1)
        #pragma unroll
        for (int s = 0; s < 16; ++s)
            best[s] = umn(best[s], (unsigned)__shfl_xor((int)best[s], mm, 64));

    if (m == 0) {
        unsigned* dst = isPos ? posk : negk;
        #pragma unroll
        for (int u = 0; u < 4; ++u)
            #pragma unroll
            for (int r = 0; r < 4; ++r) {
                int orig = pm[ab + u * 16 + quad * 4 + r];
                if ((unsigned)orig < (unsigned)N)          // pad anchors: perm=-1
                    dst[orig] = best[u * 4 + r] ^ inv;
            }
    }
}

// ---------------- kernel 3: hinge + last-block deterministic reduce ----------
// 512 blocks x 4 waves x 4 rows/wave, FULLY unrolled with batched loads: all
// posk/negk, then all invn, then all 12 row-gathers issued independently —
// r7's 32-deep serial dependent chain (43us @1.85% occupancy) becomes ~3
// latencies per wave at 2 blocks/CU. Release: one __threadfence per BLOCK
// (after __syncthreads drained each wave's stores), not per thread — r1 showed
// mass device fences cost ~18ns each. Last block = r4 k_reduce body verbatim.
__global__ __launch_bounds__(256) void k_finred(const float* __restrict__ z,
                                                const float* __restrict__ invn,
                                                const unsigned* __restrict__ posk,
                                                const unsigned* __restrict__ negk,
                                                float* __restrict__ per, float* __restrict__ vld,
                                                unsigned* __restrict__ tick,
                                                float* __restrict__ out) {
    __shared__ float s1[256], s2[256];
    __shared__ int amLast;
    const int t    = threadIdx.x;
    const int wv   = t >> 6, lane = t & 63;
    const int base = blockIdx.x * RPF + wv * 4;   // 4 rows per wave

    // batched independent loads for all 4 rows
    unsigned mp[4], mn[4];
    #pragma unroll
    for (int r = 0; r < 4; ++r) { mp[r] = posk[base + r]; mn[r] = negk[base + r]; }
    bool valid[4]; int pi[4], ni[4];
    #pragma unroll
    for (int r = 0; r < 4; ++r) {
        valid[r] = (mp[r] != 0xFFFFFFFFu) && (mn[r] != 0u);
        pi[r] = valid[r] ? (int)(mp[r] & 8191u) : 0;
        ni[r] = valid[r] ? (int)(mn[r] & 8191u) : 0;
    }
    float ia[4], ip[4], iq[4];
    #pragma unroll
    for (int r = 0; r < 4; ++r) { ia[r] = invn[base + r]; ip[r] = invn[pi[r]]; iq[r] = invn[ni[r]]; }
    float2 a[4], p[4], q[4];
    #pragma unroll
    for (int r = 0; r < 4; ++r) {
        a[r] = ((const float2*)(z + (size_t)(base + r) * D))[lane];
        p[r] = ((const float2*)(z + (size_t)pi[r] * D))[lane];
        q[r] = ((const float2*)(z + (size_t)ni[r] * D))[lane];
    }
    #pragma unroll
    for (int r = 0; r < 4; ++r) {
        float dx = a[r].x * ia[r] - p[r].x * ip[r] + PD_EPS;
        float dy = a[r].y * ia[r] - p[r].y * ip[r] + PD_EPS;
        float sap = dx * dx + dy * dy;
        dx = a[r].x * ia[r] - q[r].x * iq[r] + PD_EPS;
        dy = a[r].y * ia[r] - q[r].y * iq[r] + PD_EPS;
        float san = dx * dx + dy * dy;
        #pragma unroll
        for (int m = 1; m < 64; m <<= 1) {
            sap += __shfl_xor(sap, m, 64);
            san += __shfl_xor(san, m, 64);
        }
        if (lane == 0) {
            float l = fmaxf(sqrtf(sap) - sqrtf(san) + MARGIN, 0.0f);
            per[base + r] = valid[r] ? l : 0.0f;
            vld[base + r] = valid[r] ? 1.0f : 0.0f;
        }
    }

    __syncthreads();               // drains each wave's stores (vmcnt(0) before barrier)
    if (t == 0) {
        __threadfence();           // single release fence per block (writes now in L2)
        amLast = (atomicInc(tick + 3, FBLK - 1) == FBLK - 1);  // wraps to 0
    }
    __syncthreads();
    if (amLast) {
        __threadfence();           // acquire: see all other blocks' per/vld
        float a2 = 0.f, b2 = 0.f;
        for (int i = t; i < N; i += 256) { a2 += per[i]; b2 += vld[i]; }
        s1[t] = a2; s2[t] = b2;
        __syncthreads();
        for (int w = 128; w > 0; w >>= 1) {
            if (t < w) { s1[t] += s1[t + w]; s2[t] += s2[t + w]; }
            __syncthreads();
        }
        if (t == 0) {
            float cnt = s2[0];
            out[0] = (cnt > 0.f) ? s1[0] / fmaxf(cnt, 1.f) : 0.f;
        }
    }
}

extern "C" void kernel_launch(void* const* d_in, const int* in_sizes, int n_in,
                              void* d_out, int out_size, void* d_ws, size_t ws_size,
                              hipStream_t stream) {
    const float* z        = (const float*)d_in[0];
    const int*   labels   = (const int*)d_in[1];
    const int*   subjects = (const int*)d_in[2];
    float* out = (float*)d_out;

    char* ws = (char*)d_ws;
    size_t o = 0;
    unsigned short* znbL = (unsigned short*)(ws + o); o += (size_t)NLAB * CAPL * D * 2;  // 4 MB
    unsigned short* znbS = (unsigned short*)(ws + o); o += (size_t)NSUB * CAPS * D * 2;  // 4 MB
    float* invn = (float*)(ws + o); o += N * 4;
    unsigned* posk = (unsigned*)(ws + o); o += N * 4;
    unsigned* negk = (unsigned*)(ws + o); o += N * 4;
    float* per = (float*)(ws + o); o += N * 4;
    float* vld = (float*)(ws + o); o += N * 4;
    // ---- 0xFF-memset region: meta/perm pads (-1) + padded counters (-1) ----
    char* padbase = ws + o;
    int* metaL = (int*)(ws + o); o += NLAB * CAPL * 4;    // 64 KB
    int* permL = (int*)(ws + o); o += NLAB * CAPL * 4;    // 64 KB
    int* metaS = (int*)(ws + o); o += NSUB * CAPS * 4;    // 64 KB
    int* permS = (int*)(ws + o); o += NSUB * CAPS * 4;    // 64 KB
    int* cnt   = (int*)(ws + o); o += (NLAB + NSUB) * CSTRIDE * 4;   // 6 KB, 1 cnt / 128B line
    size_t padbytes = (size_t)((char*)(ws + o) - padbase);
    unsigned* tick = (unsigned*)(ws + o); o += 64;        // total ~8.7 MB

    hipMemsetAsync(padbase, 0xFF, padbytes, stream);
    k_scatnorm<<<dim3(N / 4), dim3(256), 0, stream>>>(z, labels, subjects, znbL, znbS, invn,
                                                      metaL, permL, metaS, permS, cnt, tick);
    k_mine<<<dim3(MINEBLOCKS), dim3(256), 0, stream>>>(znbL, znbS, metaL, permL, metaS, permS,
                                                       posk, negk);
    k_finred<<<dim3(FBLK), dim3(256), 0, stream>>>(z, invn, posk, negk, per, vld, tick, out);
}